// Round 7
// baseline (412.205 us; speedup 1.0000x reference)
//
#include <hip/hip_runtime.h>
#include <math.h>

// Problem constants (b, n, m) = (16, 2048, 2048); scores is (16, 2049, 2049) fp32.
#define BATCH 16
#define NN 2048
#define MM 2048
#define WW 2049
#define GAMMA 0.5f
#define RPB 16          // rows per block (last block takes 17)
#define NBX 128         // row-chunks per batch

// *** R7 = CALIBRATION ROUND ***
// main_kernel reads 4x the data (passes 1-3 stream batches (b+1..3)&15 into a
// dummy kept alive via asm volatile). Output path is bit-identical to R6.
// Purpose: push main above the harness's 160us fills so its own rocprof row
// (hbm_gbps, VGPR, occupancy, VALUBusy) appears in top-5, and decompose
// dur_us into harness floor vs kernel time: main_true = (dur_us - 386)/3.

// --- Kernel 1: gather q0/q1 (pos - GAMMA).
__global__ __launch_bounds__(256) void gather_kernel(
    const float* __restrict__ scores, const int* __restrict__ gt0,
    const int* __restrict__ gt1, float* __restrict__ q0, float* __restrict__ q1)
{
    int id = blockIdx.x * 256 + threadIdx.x;
    const int half = BATCH * NN;
    if (id < half) {
        int b = id >> 11, i = id & (NN - 1);
        int g = gt0[id];
        g = (g == -1) ? MM : g;
        g = min(max(g, 0), MM);
        q0[id] = scores[(size_t)b * WW * WW + (size_t)i * WW + g] - GAMMA;
    } else {
        int id2 = id - half;
        int b = id2 >> 11, j = id2 & (MM - 1);
        int g = gt1[id2];
        g = (g == -1) ? NN : g;
        g = min(max(g, 0), NN);
        q1[id2] = scores[(size_t)b * WW * WW + (size_t)g * WW + j] - GAMMA;
    }
}

// --- Kernel 2: single pass (pass 0) + 3 calibration streaming passes.
__global__ __launch_bounds__(256) void main_kernel(
    const float* __restrict__ scores, const float* __restrict__ q0,
    const float* __restrict__ q1, float* __restrict__ colpart,
    float* __restrict__ rowpart)
{
    const int b = blockIdx.y;
    const int bx = blockIdx.x;
    const int row0 = bx * RPB;
    const int nrows = (bx == NBX - 1) ? (RPB + 1) : RPB;   // fold row 2048
    const int tid = threadIdx.x;
    const int wave = tid >> 6;
    const int lane = tid & 63;
    const int col0 = 512 * wave + lane;                    // + 64*k, k=0..7

    const size_t bstride = (size_t)WW * WW;
    const float* sb  = scores + (size_t)b * bstride;
    const float* q0b = q0 + b * NN;
    const float* q1b = q1 + b * MM;

    // calibration bases: same rows, other batches (distinct HBM lines)
    const size_t roff = (size_t)row0 * WW + col0;
    const float* rowp  = sb + roff;
    const float* rowp1 = scores + (size_t)((b + 1) & 15) * bstride + roff;
    const float* rowp2 = scores + (size_t)((b + 2) & 15) * bstride + roff;
    const float* rowp3 = scores + (size_t)((b + 3) & 15) * bstride + roff;

    float q1v[8], colacc[8];
#pragma unroll
    for (int k = 0; k < 8; ++k) { q1v[k] = q1b[col0 + 64 * k]; colacc[k] = 0.0f; }

    __shared__ float part[4][RPB + 1];
    float dummy = 0.0f;

    for (int r = 0; r < nrows; ++r) {
        const int i = row0 + r;
        const bool has_row = (i < NN);                     // i==2048: col-only
        const float q0i = has_row ? q0b[i] : 0.0f;

        float s[8], d1[8], d2[8], d3[8];
#pragma unroll
        for (int k = 0; k < 8; ++k) s[k]  = rowp [64 * k];
#pragma unroll
        for (int k = 0; k < 8; ++k) d1[k] = rowp1[64 * k];
#pragma unroll
        for (int k = 0; k < 8; ++k) d2[k] = rowp2[64 * k];
#pragma unroll
        for (int k = 0; k < 8; ++k) d3[k] = rowp3[64 * k];

        float t = 0.0f;
#pragma unroll
        for (int k = 0; k < 8; ++k) {
            t += fmaxf(s[k], q0i);                         // row contribution
            colacc[k] += fmaxf(s[k], q1v[k]);              // col contribution
        }
#pragma unroll
        for (int k = 0; k < 8; ++k)                        // calibration sink
            dummy += d1[k] + d2[k] + d3[k];

        if (wave == 0 && lane == 0)                        // j==2048 (row-only)
            t += fmaxf(sb[(size_t)i * WW + 2048], q0i);
#pragma unroll
        for (int off = 32; off; off >>= 1)
            t += __shfl_xor(t, off);
        if (lane == 0) part[wave][r] = t;
        rowp += WW; rowp1 += WW; rowp2 += WW; rowp3 += WW;
    }
    asm volatile("" :: "v"(dummy));   // keep calibration loads alive (no DCE)
    __syncthreads();

    // Row terms: wave 0, lane r handles row row0+r.
    if (wave == 0) {
        float term = 0.0f;
        if (lane < nrows) {
            const int i = row0 + lane;
            if (i < NN) {
                const float rs = part[0][lane] + part[1][lane]
                               + part[2][lane] + part[3][lane];
                term = 2.0f * logf(rs - 2049.0f * q0b[i] + 0.5f);
            }
        }
#pragma unroll
        for (int off = 32; off; off >>= 1)
            term += __shfl_xor(term, off);
        if (lane == 0) rowpart[bx * BATCH + b] = term;
    }

    // Column partials: plain coalesced stores to this block's private slice.
    float* dst = colpart + ((size_t)bx * BATCH + b) * MM + col0;
#pragma unroll
    for (int k = 0; k < 8; ++k) dst[64 * k] = colacc[k];
}

// --- Kernel 3: reduce the 128 block partials per column, log, block-reduce.
__global__ __launch_bounds__(256) void reduce_cols_kernel(
    const float* __restrict__ colpart, const float* __restrict__ q1,
    float* __restrict__ colterm)
{
    const int b = blockIdx.y;
    const int j = blockIdx.x * 256 + threadIdx.x;
    const int tid = threadIdx.x;
    const int wave = tid >> 6;
    const int lane = tid & 63;

    float s0 = 0.0f, s1 = 0.0f, s2 = 0.0f, s3 = 0.0f;
#pragma unroll 8
    for (int bx = 0; bx < NBX; bx += 4) {
        s0 += colpart[((size_t)(bx + 0) * BATCH + b) * MM + j];
        s1 += colpart[((size_t)(bx + 1) * BATCH + b) * MM + j];
        s2 += colpart[((size_t)(bx + 2) * BATCH + b) * MM + j];
        s3 += colpart[((size_t)(bx + 3) * BATCH + b) * MM + j];
    }
    const float cs = (s0 + s1) + (s2 + s3);
    float term = 2.0f * logf(cs - 2049.0f * q1[b * MM + j] + 0.5f);

#pragma unroll
    for (int off = 32; off; off >>= 1)
        term += __shfl_xor(term, off);

    __shared__ float red[4];
    if (lane == 0) red[wave] = term;
    __syncthreads();
    if (tid == 0)
        colterm[b * 8 + blockIdx.x] = red[0] + red[1] + red[2] + red[3];
}

// --- Kernel 4: final combine. 16 blocks x 64 threads.
__global__ __launch_bounds__(64) void final_kernel(
    const float* __restrict__ rowpart, const float* __restrict__ colterm,
    float* __restrict__ out)
{
    const int b = blockIdx.x;
    const int lane = threadIdx.x;

    float rs = rowpart[lane * BATCH + b] + rowpart[(lane + 64) * BATCH + b];
    float cs = (lane < 8) ? colterm[b * 8 + lane] : 0.0f;
#pragma unroll
    for (int off = 32; off; off >>= 1) {
        rs += __shfl_xor(rs, off);
        cs += __shfl_xor(cs, off);
    }
    if (lane == 0)
        out[b] = 0.5f * (rs * (1.0f / NN) + cs * (1.0f / MM));
}

extern "C" void kernel_launch(void* const* d_in, const int* in_sizes, int n_in,
                              void* d_out, int out_size, void* d_ws, size_t ws_size,
                              hipStream_t stream) {
    const int* gt0 = (const int*)d_in[0];
    const int* gt1 = (const int*)d_in[1];
    const float* scores = (const float*)d_in[2];
    float* out = (float*)d_out;

    float* ws = (float*)d_ws;
    float* q0      = ws;
    float* q1      = q0 + (size_t)BATCH * NN;
    float* colpart = q1 + (size_t)BATCH * MM;
    float* rowpart = colpart + (size_t)NBX * BATCH * MM;
    float* colterm = rowpart + (size_t)NBX * BATCH;

    gather_kernel<<<(2 * BATCH * NN) / 256, 256, 0, stream>>>(scores, gt0, gt1, q0, q1);

    dim3 grid(NBX, BATCH);
    main_kernel<<<grid, 256, 0, stream>>>(scores, q0, q1, colpart, rowpart);

    dim3 rgrid(8, BATCH);
    reduce_cols_kernel<<<rgrid, 256, 0, stream>>>(colpart, q1, colterm);

    final_kernel<<<BATCH, 64, 0, stream>>>(rowpart, colterm, out);
}